// Round 8
// baseline (502.071 us; speedup 1.0000x reference)
//
#include <hip/hip_runtime.h>

#define NN 131072   // total nodes (256 graphs x 512)
#define NE 1048576  // edges
// ws layout (bytes); total = 0x4200000 (~69 MB)
#define OFF_DEG_OUT 0x000000   // int[NN]
#define OFF_CURSOR  0x080000   // int[NN] -> becomes deg_in
#define OFF_WT      0x100000   // bf16 3x[128][128] transposed layer weights (96 KB)
#define OFF_WTI     0x118000   // bf16 [128][96] transposed init weight, K-padded (24 KB)
#define OFF_BUCKET  0x200000   // int[NN][64] adjacency buckets (33.5 MB)
#define OFF_HN      0x2200000  // bf16[NN][128] (33.5 MB)

typedef __attribute__((ext_vector_type(8))) short bf16x8;
typedef __attribute__((ext_vector_type(4))) float f32x4;

static __device__ __forceinline__ float blo(unsigned u){ return __uint_as_float(u << 16); }
static __device__ __forceinline__ float bhi(unsigned u){ return __uint_as_float(u & 0xffff0000u); }
static __device__ __forceinline__ unsigned f2b(float f){
    unsigned u = __float_as_uint(f);
    return (u + 0x7fffu + ((u >> 16) & 1u)) >> 16;   // round-to-nearest-even
}
static __device__ __forceinline__ unsigned pack2(float a, float b){
    return f2b(a) | (f2b(b) << 16);
}

// deg_out count + bucketed CSR build; 2 edges/thread (r6 sweet spot: 90 us, 57% occ)
__global__ __launch_bounds__(256) void k_fill(const int* __restrict__ src,
                                              const int* __restrict__ dst,
                                              int* __restrict__ deg_out,
                                              int* __restrict__ cursor,
                                              int* __restrict__ bucket) {
    int base = (blockIdx.x * 256 + threadIdx.x) * 2;
    int2 s2 = *(const int2*)&src[base];
    int2 d2 = *(const int2*)&dst[base];
    int p0 = atomicAdd(&cursor[d2.x], 1);
    int p1 = atomicAdd(&cursor[d2.y], 1);
    atomicAdd(&deg_out[s2.x], 1);
    atomicAdd(&deg_out[s2.y], 1);
    if (p0 < 64) bucket[(size_t)d2.x * 64 + p0] = s2.x;   // deg>=64 has P~1e-40
    if (p1 < 64) bucket[(size_t)d2.y * 64 + p1] = s2.y;
}

// all weight transposes in one launch: Wt[L][n][k] (layers) + Wti[n][k0..95] (init, K-padded)
__global__ __launch_bounds__(256) void k_wprep(const float* __restrict__ W1,
                                               const float* __restrict__ W2,
                                               const float* __restrict__ W3,
                                               const float* __restrict__ Wi,
                                               unsigned short* __restrict__ Wt,
                                               unsigned short* __restrict__ Wti) {
    int idx = blockIdx.x * 256 + threadIdx.x;
    if (idx < 49152) {
        int L = idx >> 14, rem = idx & 16383;
        int k = rem >> 7, n = rem & 127;
        const float* W = L == 0 ? W1 : (L == 1 ? W2 : W3);
        Wt[L * 16384 + n * 128 + k] = (unsigned short)f2b(W[k * 128 + n]);
    } else if (idx < 61440) {
        int rem = idx - 49152;
        int n = rem / 96, k = rem - n * 96;
        float v = (k < 74) ? Wi[k * 128 + n] : 0.f;
        Wti[n * 96 + k] = (unsigned short)f2b(v);
    }
}

// hn0 = bf16((x @ W_init) * deg_out^-1/2) via MFMA; X staged+quantized in LDS, K->96
__global__ __launch_bounds__(256) void k_init(const float* __restrict__ X,
                                              const unsigned short* __restrict__ Wti,
                                              const int* __restrict__ deg_out,
                                              unsigned short* __restrict__ hn) {
    __shared__ unsigned int xs[64 * 68];   // 17.4 KB; staging + epilogue reuse
    int tid = threadIdx.x;
    int m0 = blockIdx.x * 64;

    for (int idx = tid; idx < 2368; idx += 256) {        // X: 64 rows x 37 float2, quantize
        int m = idx / 37, t = idx - m * 37;
        float2 v = *(const float2*)&X[(size_t)(m0 + m) * 74 + t * 2];
        xs[m * 68 + t] = pack2(v.x, v.y);
    }
    for (int idx = tid; idx < 64 * 11; idx += 256) {     // zero pad words 37..47 (K 74..95)
        int m = idx / 11, c = 37 + idx % 11;
        xs[m * 68 + c] = 0u;
    }
    __syncthreads();

    int wave = tid >> 6, lane = tid & 63, quad = lane >> 4, l16 = lane & 15;
    f32x4 acc[8];
    #pragma unroll
    for (int t = 0; t < 8; ++t) acc[t] = (f32x4){0.f, 0.f, 0.f, 0.f};
    int arow = (wave * 16 + l16) * 68 + quad * 4;
    #pragma unroll
    for (int ks = 0; ks < 3; ++ks) {
        bf16x8 af = *(const bf16x8*)&xs[arow + ks * 16];
        #pragma unroll
        for (int t = 0; t < 8; ++t) {
            bf16x8 bf = *(const bf16x8*)(Wti + (t * 16 + l16) * 96 + ks * 32 + quad * 8);
            acc[t] = __builtin_amdgcn_mfma_f32_16x16x32_bf16(af, bf, acc[t], 0, 0, 0);
        }
    }
    __syncthreads();   // done reading xs; reuse as bf16 epilogue tile [64][136 shorts]
    unsigned short* atb = (unsigned short*)xs;
    int mb = wave * 16 + quad * 4;
    float nsr[4];
    #pragma unroll
    for (int r = 0; r < 4; ++r) {
        int dq = deg_out[m0 + mb + r];
        nsr[r] = rsqrtf((float)(dq > 1 ? dq : 1));
    }
    #pragma unroll
    for (int t = 0; t < 8; ++t)
        #pragma unroll
        for (int r = 0; r < 4; ++r)
            atb[(mb + r) * 136 + t * 16 + l16] = (unsigned short)f2b(acc[t][r] * nsr[r]);
    __syncthreads();
    {   // coalesced write-out: thread -> row tid>>2, 64-B slice (tid&3)
        int r = tid >> 2, c0 = (tid & 3) * 32;
        unsigned int* sp = &xs[r * 68 + (tid & 3) * 16];
        #pragma unroll
        for (int j = 0; j < 4; ++j)
            *(uint4*)(hn + (size_t)(m0 + r) * 128 + c0 + j * 8) = *(const uint4*)(sp + j * 4);
    }
}

// fused layer: wave-per-node gather with SGPR row addresses, MFMA vs global Wt
__global__ __launch_bounds__(256) void k_layer(const unsigned short* __restrict__ hn,
                                               const int* __restrict__ bucket,
                                               const int* __restrict__ deg_in,
                                               const int* __restrict__ deg_out,
                                               const unsigned short* __restrict__ Wt,
                                               const float* __restrict__ bias,
                                               void* __restrict__ OutP, int last) {
    __shared__ unsigned int at[64 * 68];   // 17.4 KB bf16 A-tile, row stride 68 words
    int tid = threadIdx.x;
    int wave = tid >> 6, lane = tid & 63;
    int m0 = blockIdx.x * 64;

    // phase 1: one wave per node row; lane owns one bf16 column pair (4 B of the 256-B row).
    // Row index comes from readlane -> SGPR base -> scalar-addressed row load, 8 in flight.
    for (int i = 0; i < 16; ++i) {
        int nl = wave * 16 + i;
        int n = m0 + nl;
        int cnt = deg_in[n];
        cnt = cnt < 64 ? cnt : 64;
        int myidx = bucket[(size_t)n * 64 + lane];   // whole bucket row, 1 inst
        float a0 = 0.f, a1 = 0.f;
        for (int c = 0; c < cnt; c += 8) {
            unsigned v[8];
            float w[8];
            #pragma unroll
            for (int j = 0; j < 8; ++j) {
                int jj = c + j;
                int s = jj < cnt ? __builtin_amdgcn_readlane(myidx, jj) : 0;  // uniform
                w[j] = jj < cnt ? 1.f : 0.f;
                v[j] = *(const unsigned*)(hn + (size_t)s * 128 + lane * 2);
            }
            #pragma unroll
            for (int j = 0; j < 8; ++j) {
                a0 = fmaf(w[j], blo(v[j]), a0);
                a1 = fmaf(w[j], bhi(v[j]), a1);
            }
        }
        float nd = rsqrtf((float)(cnt > 1 ? cnt : 1));
        at[nl * 68 + lane] = pack2(a0 * nd, a1 * nd);
    }
    __syncthreads();

    // phase 2: MFMA 64x128; B-frags straight from global Wt (L2-hot, 32 KB)
    f32x4 acc[8];
    #pragma unroll
    for (int t = 0; t < 8; ++t) acc[t] = (f32x4){0.f, 0.f, 0.f, 0.f};
    int quad = lane >> 4, l16 = lane & 15;
    int arow = (wave * 16 + l16) * 68 + quad * 4;
    #pragma unroll
    for (int ks = 0; ks < 4; ++ks) {
        bf16x8 af = *(const bf16x8*)&at[arow + ks * 16];
        #pragma unroll
        for (int t = 0; t < 8; ++t) {
            bf16x8 bf = *(const bf16x8*)(Wt + (t * 16 + l16) * 128 + ks * 32 + quad * 8);
            acc[t] = __builtin_amdgcn_mfma_f32_16x16x32_bf16(af, bf, acc[t], 0, 0, 0);
        }
    }

    int mb = wave * 16 + quad * 4;
    if (!last) {
        // bf16 out: LDS transpose (reuse A-tile) -> coalesced uint4 stores
        float nsr[4];
        #pragma unroll
        for (int r = 0; r < 4; ++r) {
            int dq = deg_out[m0 + mb + r];
            nsr[r] = rsqrtf((float)(dq > 1 ? dq : 1));
        }
        __syncthreads();   // all waves done reading A-tile
        unsigned short* atb = (unsigned short*)at;
        #pragma unroll
        for (int t = 0; t < 8; ++t) {
            float bv = bias[t * 16 + l16];
            #pragma unroll
            for (int r = 0; r < 4; ++r) {
                float v = acc[t][r] + bv;
                v = (v > 0.f ? v : 0.f) * nsr[r];
                atb[(mb + r) * 136 + t * 16 + l16] = (unsigned short)f2b(v);
            }
        }
        __syncthreads();
        int r = tid >> 2, c0 = (tid & 3) * 32;
        unsigned short* Out = (unsigned short*)OutP;
        unsigned int* sp = &at[r * 68 + (tid & 3) * 16];
        #pragma unroll
        for (int j = 0; j < 4; ++j)
            *(uint4*)(Out + (size_t)(m0 + r) * 128 + c0 + j * 8) = *(const uint4*)(sp + j * 4);
    } else {
        // fp32 out: direct C-layout stores are full 64-B sectors; nontemporal (read-never)
        float* Out = (float*)OutP;
        #pragma unroll
        for (int t = 0; t < 8; ++t) {
            float bv = bias[t * 16 + l16];
            #pragma unroll
            for (int r = 0; r < 4; ++r) {
                float v = acc[t][r] + bv;
                v = v > 0.f ? v : 0.f;
                __builtin_nontemporal_store(v, &Out[(size_t)(m0 + mb + r) * 128 + t * 16 + l16]);
            }
        }
    }
}

extern "C" void kernel_launch(void* const* d_in, const int* in_sizes, int n_in,
                              void* d_out, int out_size, void* d_ws, size_t ws_size,
                              hipStream_t stream) {
    const float* x  = (const float*)d_in[0];
    const int* src  = (const int*)d_in[1];
    const int* dst  = (const int*)d_in[2];
    const float* Wi = (const float*)d_in[3];
    const float* W1 = (const float*)d_in[4];
    const float* b1 = (const float*)d_in[5];
    const float* W2 = (const float*)d_in[6];
    const float* b2 = (const float*)d_in[7];
    const float* W3 = (const float*)d_in[8];
    const float* b3 = (const float*)d_in[9];

    char* ws = (char*)d_ws;
    int* deg_out   = (int*)(ws + OFF_DEG_OUT);
    int* cursor    = (int*)(ws + OFF_CURSOR);   // becomes deg_in
    unsigned short* Wt  = (unsigned short*)(ws + OFF_WT);
    unsigned short* Wti = (unsigned short*)(ws + OFF_WTI);
    int* bucket    = (int*)(ws + OFF_BUCKET);
    unsigned short* hnA = (unsigned short*)(ws + OFF_HN);
    unsigned short* hnB = (unsigned short*)d_out;   // bf16 ping buffer inside d_out

    hipMemsetAsync(ws, 0, 0x100000, stream);        // zero deg_out + cursor
    k_fill<<<NE / 512, 256, 0, stream>>>(src, dst, deg_out, cursor, bucket);
    k_wprep<<<240, 256, 0, stream>>>(W1, W2, W3, Wi, Wt, Wti);
    k_init<<<NN / 64, 256, 0, stream>>>(x, Wti, deg_out, hnA);

    const float* bl[3] = {b1, b2, b3};
    // ping-pong: L0 hnA->hnB(bf16), L1 hnB->hnA, L2 hnA->d_out(fp32)
    k_layer<<<NN / 64, 256, 0, stream>>>(hnA, bucket, cursor, deg_out,
                                         Wt,         bl[0], (void*)hnB, 0);
    k_layer<<<NN / 64, 256, 0, stream>>>(hnB, bucket, cursor, deg_out,
                                         Wt + 16384, bl[1], (void*)hnA, 0);
    k_layer<<<NN / 64, 256, 0, stream>>>(hnA, bucket, cursor, deg_out,
                                         Wt + 32768, bl[2], d_out, 1);
}

// Round 9
// 475.236 us; speedup vs baseline: 1.0565x; 1.0565x over previous
//
#include <hip/hip_runtime.h>

#define NN 131072   // total nodes (256 graphs x 512)
#define NE 1048576  // edges
// ws layout (bytes); total = 0x4200000 (~69 MB, size verified by rounds 2-8)
#define OFF_DEG_OUT 0x000000   // int[NN]
#define OFF_CURSOR  0x080000   // int[NN] -> becomes deg_in
#define OFF_WT      0x100000   // bf16 3x[128][128] transposed layer weights (96 KB)
#define OFF_WTI     0x118000   // bf16 [128][96] transposed init weight, K-padded (24 KB)
#define OFF_BUCKET  0x200000   // int[NN][64] adjacency buckets (33.5 MB)
#define OFF_AGG     0x2200000  // bf16[NN][128] aggregated messages (33.5 MB)
// hn (bf16[NN][128]) lives in the lower half of d_out; dead before final fp32 write.

typedef __attribute__((ext_vector_type(8))) short bf16x8;
typedef __attribute__((ext_vector_type(4))) float f32x4;

static __device__ __forceinline__ float blo(unsigned u){ return __uint_as_float(u << 16); }
static __device__ __forceinline__ float bhi(unsigned u){ return __uint_as_float(u & 0xffff0000u); }
static __device__ __forceinline__ unsigned f2b(float f){
    unsigned u = __float_as_uint(f);
    return (u + 0x7fffu + ((u >> 16) & 1u)) >> 16;   // round-to-nearest-even
}
static __device__ __forceinline__ unsigned pack2(float a, float b){
    return f2b(a) | (f2b(b) << 16);
}

// deg_out count + bucketed CSR build; 2 edges/thread (r6 sweet spot: 90 us, 57% occ)
__global__ __launch_bounds__(256) void k_fill(const int* __restrict__ src,
                                              const int* __restrict__ dst,
                                              int* __restrict__ deg_out,
                                              int* __restrict__ cursor,
                                              int* __restrict__ bucket) {
    int base = (blockIdx.x * 256 + threadIdx.x) * 2;
    int2 s2 = *(const int2*)&src[base];
    int2 d2 = *(const int2*)&dst[base];
    int p0 = atomicAdd(&cursor[d2.x], 1);
    int p1 = atomicAdd(&cursor[d2.y], 1);
    atomicAdd(&deg_out[s2.x], 1);
    atomicAdd(&deg_out[s2.y], 1);
    if (p0 < 64) bucket[(size_t)d2.x * 64 + p0] = s2.x;   // deg>=64 has P~1e-40
    if (p1 < 64) bucket[(size_t)d2.y * 64 + p1] = s2.y;
}

// all weight transposes in one launch: Wt[L][n][k] (layers) + Wti[n][k0..95] (init, K-padded)
__global__ __launch_bounds__(256) void k_wprep(const float* __restrict__ W1,
                                               const float* __restrict__ W2,
                                               const float* __restrict__ W3,
                                               const float* __restrict__ Wi,
                                               unsigned short* __restrict__ Wt,
                                               unsigned short* __restrict__ Wti) {
    int idx = blockIdx.x * 256 + threadIdx.x;
    if (idx < 49152) {
        int L = idx >> 14, rem = idx & 16383;
        int k = rem >> 7, n = rem & 127;
        const float* W = L == 0 ? W1 : (L == 1 ? W2 : W3);
        Wt[L * 16384 + n * 128 + k] = (unsigned short)f2b(W[k * 128 + n]);
    } else if (idx < 61440) {
        int rem = idx - 49152;
        int n = rem / 96, k = rem - n * 96;
        float v = (k < 74) ? Wi[k * 128 + n] : 0.f;
        Wti[n * 96 + k] = (unsigned short)f2b(v);
    }
}

// hn0 = bf16((x @ W_init) * deg_out^-1/2) via MFMA; X staged+quantized in LDS, K->96
__global__ __launch_bounds__(256) void k_init(const float* __restrict__ X,
                                              const unsigned short* __restrict__ Wti,
                                              const int* __restrict__ deg_out,
                                              unsigned short* __restrict__ hn) {
    __shared__ unsigned int xs[64 * 68];   // 17.4 KB; staging + epilogue reuse
    int tid = threadIdx.x;
    int m0 = blockIdx.x * 64;

    for (int idx = tid; idx < 2368; idx += 256) {        // X: 64 rows x 37 float2, quantize
        int m = idx / 37, t = idx - m * 37;
        float2 v = *(const float2*)&X[(size_t)(m0 + m) * 74 + t * 2];
        xs[m * 68 + t] = pack2(v.x, v.y);
    }
    for (int idx = tid; idx < 64 * 11; idx += 256) {     // zero pad words 37..47 (K 74..95)
        int m = idx / 11, c = 37 + idx % 11;
        xs[m * 68 + c] = 0u;
    }
    __syncthreads();

    int wave = tid >> 6, lane = tid & 63, quad = lane >> 4, l16 = lane & 15;
    f32x4 acc[8];
    #pragma unroll
    for (int t = 0; t < 8; ++t) acc[t] = (f32x4){0.f, 0.f, 0.f, 0.f};
    int arow = (wave * 16 + l16) * 68 + quad * 4;
    #pragma unroll
    for (int ks = 0; ks < 3; ++ks) {
        bf16x8 af = *(const bf16x8*)&xs[arow + ks * 16];
        #pragma unroll
        for (int t = 0; t < 8; ++t) {
            bf16x8 bf = *(const bf16x8*)(Wti + (t * 16 + l16) * 96 + ks * 32 + quad * 8);
            acc[t] = __builtin_amdgcn_mfma_f32_16x16x32_bf16(af, bf, acc[t], 0, 0, 0);
        }
    }
    __syncthreads();   // done reading xs; reuse as bf16 epilogue tile [64][136 shorts]
    unsigned short* atb = (unsigned short*)xs;
    int mb = wave * 16 + quad * 4;
    float nsr[4];
    #pragma unroll
    for (int r = 0; r < 4; ++r) {
        int dq = deg_out[m0 + mb + r];
        nsr[r] = rsqrtf((float)(dq > 1 ? dq : 1));
    }
    #pragma unroll
    for (int t = 0; t < 8; ++t)
        #pragma unroll
        for (int r = 0; r < 4; ++r)
            atb[(mb + r) * 136 + t * 16 + l16] = (unsigned short)f2b(acc[t][r] * nsr[r]);
    __syncthreads();
    {   // coalesced write-out: thread -> row tid>>2, 64-B slice (tid&3)
        int r = tid >> 2, c0 = (tid & 3) * 32;
        unsigned int* sp = &xs[r * 68 + (tid & 3) * 16];
        #pragma unroll
        for (int j = 0; j < 4; ++j)
            *(uint4*)(hn + (size_t)(m0 + r) * 128 + c0 + j * 8) = *(const uint4*)(sp + j * 4);
    }
}

// standalone gather (r2's proven 3.7 TB/s shape, bf16 rows): 32 lanes/node, uint2/lane,
// no LDS, low VGPR -> max occupancy; branch-free unroll-4 for MLP
__global__ __launch_bounds__(256) void k_agg(const uint2* __restrict__ hn2,
                                             const int* __restrict__ bucket,
                                             const int* __restrict__ deg_in,
                                             uint2* __restrict__ agg) {
    int g = threadIdx.x >> 5;
    int lane = threadIdx.x & 31;
    int n = blockIdx.x * 8 + g;
    int cnt = deg_in[n];
    cnt = cnt < 64 ? cnt : 64;
    const int* brow = bucket + (size_t)n * 64;
    float a0 = 0.f, a1 = 0.f, a2 = 0.f, a3 = 0.f;
    for (int c = 0; c < cnt; c += 4) {
        int4 i4 = *(const int4*)&brow[c];
        int lim = cnt - c;
        int s1 = lim > 1 ? i4.y : 0;
        int s2 = lim > 2 ? i4.z : 0;
        int s3 = lim > 3 ? i4.w : 0;
        uint2 v0 = hn2[(size_t)i4.x * 32 + lane];
        uint2 v1 = hn2[(size_t)s1 * 32 + lane];
        uint2 v2 = hn2[(size_t)s2 * 32 + lane];
        uint2 v3 = hn2[(size_t)s3 * 32 + lane];
        float w1 = lim > 1 ? 1.f : 0.f;
        float w2 = lim > 2 ? 1.f : 0.f;
        float w3 = lim > 3 ? 1.f : 0.f;
        a0 += blo(v0.x); a1 += bhi(v0.x); a2 += blo(v0.y); a3 += bhi(v0.y);
        a0 = fmaf(w1, blo(v1.x), a0); a1 = fmaf(w1, bhi(v1.x), a1);
        a2 = fmaf(w1, blo(v1.y), a2); a3 = fmaf(w1, bhi(v1.y), a3);
        a0 = fmaf(w2, blo(v2.x), a0); a1 = fmaf(w2, bhi(v2.x), a1);
        a2 = fmaf(w2, blo(v2.y), a2); a3 = fmaf(w2, bhi(v2.y), a3);
        a0 = fmaf(w3, blo(v3.x), a0); a1 = fmaf(w3, bhi(v3.x), a1);
        a2 = fmaf(w3, blo(v3.y), a2); a3 = fmaf(w3, bhi(v3.y), a3);
    }
    float nd = rsqrtf((float)(cnt > 1 ? cnt : 1));
    uint2 o;
    o.x = pack2(a0 * nd, a1 * nd);
    o.y = pack2(a2 * nd, a3 * nd);
    agg[(size_t)n * 32 + lane] = o;
}

// standalone MFMA GEMM: Out = relu(agg @ W + b) (*deg_out^-1/2 unless last)
// A-frags direct from global agg (streaming), B-frags direct from global Wt (L2-hot)
__global__ __launch_bounds__(256) void k_gemm(const unsigned short* __restrict__ A,
                                              const unsigned short* __restrict__ Wt,
                                              const int* __restrict__ deg_out,
                                              const float* __restrict__ bias,
                                              void* __restrict__ OutP, int last) {
    __shared__ unsigned int ep[64 * 68];   // 17.4 KB epilogue transpose tile
    int tid = threadIdx.x;
    int wave = tid >> 6, lane = tid & 63, quad = lane >> 4, l16 = lane & 15;
    int m0 = blockIdx.x * 64;

    const unsigned short* arow = A + (size_t)(m0 + wave * 16 + l16) * 128 + quad * 8;
    bf16x8 af[4];
    #pragma unroll
    for (int ks = 0; ks < 4; ++ks) af[ks] = *(const bf16x8*)(arow + ks * 32);

    f32x4 acc[8];
    #pragma unroll
    for (int t = 0; t < 8; ++t) acc[t] = (f32x4){0.f, 0.f, 0.f, 0.f};
    #pragma unroll
    for (int ks = 0; ks < 4; ++ks)
        #pragma unroll
        for (int t = 0; t < 8; ++t) {
            bf16x8 bf = *(const bf16x8*)(Wt + (t * 16 + l16) * 128 + ks * 32 + quad * 8);
            acc[t] = __builtin_amdgcn_mfma_f32_16x16x32_bf16(af[ks], bf, acc[t], 0, 0, 0);
        }

    int mb = wave * 16 + quad * 4;
    if (!last) {
        // bf16 out: LDS transpose -> coalesced uint4 stores
        float nsr[4];
        #pragma unroll
        for (int r = 0; r < 4; ++r) {
            int dq = deg_out[m0 + mb + r];
            nsr[r] = rsqrtf((float)(dq > 1 ? dq : 1));
        }
        unsigned short* epb = (unsigned short*)ep;
        #pragma unroll
        for (int t = 0; t < 8; ++t) {
            float bv = bias[t * 16 + l16];
            #pragma unroll
            for (int r = 0; r < 4; ++r) {
                float v = acc[t][r] + bv;
                v = (v > 0.f ? v : 0.f) * nsr[r];
                epb[(mb + r) * 136 + t * 16 + l16] = (unsigned short)f2b(v);
            }
        }
        __syncthreads();
        int r = tid >> 2, c0 = (tid & 3) * 32;
        unsigned short* Out = (unsigned short*)OutP;
        unsigned int* sp = &ep[r * 68 + (tid & 3) * 16];
        #pragma unroll
        for (int j = 0; j < 4; ++j)
            *(uint4*)(Out + (size_t)(m0 + r) * 128 + c0 + j * 8) = *(const uint4*)(sp + j * 4);
    } else {
        // fp32 out: direct C-layout stores are full 64-B sectors; nontemporal (read-never)
        float* Out = (float*)OutP;
        #pragma unroll
        for (int t = 0; t < 8; ++t) {
            float bv = bias[t * 16 + l16];
            #pragma unroll
            for (int r = 0; r < 4; ++r) {
                float v = acc[t][r] + bv;
                v = v > 0.f ? v : 0.f;
                __builtin_nontemporal_store(v, &Out[(size_t)(m0 + mb + r) * 128 + t * 16 + l16]);
            }
        }
    }
}

extern "C" void kernel_launch(void* const* d_in, const int* in_sizes, int n_in,
                              void* d_out, int out_size, void* d_ws, size_t ws_size,
                              hipStream_t stream) {
    const float* x  = (const float*)d_in[0];
    const int* src  = (const int*)d_in[1];
    const int* dst  = (const int*)d_in[2];
    const float* Wi = (const float*)d_in[3];
    const float* W1 = (const float*)d_in[4];
    const float* b1 = (const float*)d_in[5];
    const float* W2 = (const float*)d_in[6];
    const float* b2 = (const float*)d_in[7];
    const float* W3 = (const float*)d_in[8];
    const float* b3 = (const float*)d_in[9];

    char* ws = (char*)d_ws;
    int* deg_out   = (int*)(ws + OFF_DEG_OUT);
    int* cursor    = (int*)(ws + OFF_CURSOR);   // becomes deg_in
    unsigned short* Wt  = (unsigned short*)(ws + OFF_WT);
    unsigned short* Wti = (unsigned short*)(ws + OFF_WTI);
    int* bucket    = (int*)(ws + OFF_BUCKET);
    unsigned short* agg = (unsigned short*)(ws + OFF_AGG);
    unsigned short* hn  = (unsigned short*)d_out;   // bf16 h buffer in d_out lower half

    hipMemsetAsync(ws, 0, 0x100000, stream);        // zero deg_out + cursor
    k_fill<<<NE / 512, 256, 0, stream>>>(src, dst, deg_out, cursor, bucket);
    k_wprep<<<240, 256, 0, stream>>>(W1, W2, W3, Wi, Wt, Wti);
    k_init<<<NN / 64, 256, 0, stream>>>(x, Wti, deg_out, hn);

    const float* bl[3] = {b1, b2, b3};
    for (int L = 0; L < 3; ++L) {
        int last = (L == 2);
        k_agg<<<NN / 8, 256, 0, stream>>>((const uint2*)hn, bucket, cursor, (uint2*)agg);
        k_gemm<<<NN / 64, 256, 0, stream>>>(agg, Wt + L * 16384, deg_out, bl[L],
                                            last ? d_out : (void*)hn, last);
    }
}